// Round 6
// baseline (68.835 us; speedup 1.0000x reference)
//
#include <hip/hip_runtime.h>

// YOLO decode = batched [255 x 5776] transpose + elementwise, LDS-tiled.
// B=32, A=3, C=80 -> attrs=85, CH=255, G=76, SP=5776, stride=8.
// R6: fix half-wave LDS bank conflicts in the scatter (R5 regression).
//     Lane->(c,chunk) remap: c = 4*(j>>6)+(j&3), chunk = (j>>2)&15.
//     Per 32-lane LDS phase: banks = m - 4k (m in 0..3, k in 0..7) = all 32. 
//     Global segments per wave unchanged (4 rows x 256B, lanes permuted).

#define BATCH   32
#define ATTRS   85
#define CH      255          // A * attrs
#define GRID    76
#define SP      5776         // GRID*GRID; 5776 = 64*90 + 16
#define STRIDE_F 8.0f
#define S_TILE  64
#define TPB     1024
#define TILES_PER_B ((SP + S_TILE - 1) / S_TILE)   // 91 (90 full + one 16-wide)
#define NJ_READ 4096         // 64 lane-groups of 64; covers c in [0,256) x 16 chunks
#define NF4_WRITE (CH * (S_TILE / 4))              // 4080

typedef float f4 __attribute__((ext_vector_type(4)));

__global__ __launch_bounds__(TPB, 8) void yolo_decode_kernel(
        const float* __restrict__ pred,
        const float* __restrict__ anchors,
        float* __restrict__ out) {
    __shared__ float lds[S_TILE * CH];   // transposed tile: [s_local][c], 65280 B

    const int tid = threadIdx.x;
    const int bid = blockIdx.x;
    const int b   = bid / TILES_PER_B;
    const int t   = bid - b * TILES_PER_B;
    const int s0  = t * S_TILE;
    const int sw  = (SP - s0 < S_TILE) ? (SP - s0) : S_TILE;  // 64, or 16 on last tile

    // anchors: 6 uniform floats -> registers (L1 broadcast loads, hoisted)
    const float a0x = anchors[0], a0y = anchors[1];
    const float a1x = anchors[2], a1y = anchors[3];
    const float a2x = anchors[4], a2y = anchors[5];

    // ---- read phase: coalesced f4 loads along spatial, decode, scatter to LDS ----
    // j -> (c, sl): c = 4*(j>>6) + (j&3), sl = 4*((j>>2)&15). Bijective over
    // c in [0,256) x 16 chunks; guard c<255. 4096/1024 = 4 uniform iterations.
    const float* __restrict__ src = pred + (size_t)b * (size_t)(CH * SP);
    for (int j = tid; j < NJ_READ; j += TPB) {
        const int c  = ((j >> 6) << 2) + (j & 3);
        const int sl = ((j >> 2) & 15) * 4;
        if (c >= CH) continue;           // trims the 4 phantom channels (g=63, m=3)
        if (sl >= sw) continue;          // trims only on the 16-wide partial tile

        f4 v = *(const f4*)(src + c * SP + s0 + sl);

        const int a    = c / ATTRS;      // 0,1,2
        const int attr = c - a * ATTRS;
        const float ax = (a == 0) ? a0x : (a == 1) ? a1x : a2x;
        const float ay = (a == 0) ? a0y : (a == 1) ? a1y : a2y;

        #pragma unroll
        for (int e = 0; e < 4; ++e) {
            const float val = v[e];
            const int   s   = s0 + sl + e;
            float r;
            if (attr == 2) {
                r = __expf(val) * ax;
            } else if (attr == 3) {
                r = __expf(val) * ay;
            } else {
                const float sg = __builtin_amdgcn_rcpf(1.0f + __expf(-val));
                if (attr == 0) {
                    const int x = s % GRID;
                    r = (sg + (float)x) * STRIDE_F;
                } else if (attr == 1) {
                    const int y = s / GRID;
                    r = (sg + (float)y) * STRIDE_F;
                } else {
                    r = sg;
                }
            }
            lds[(sl + e) * CH + c] = r;
        }
    }
    __syncthreads();

    // ---- write phase: output tile is one contiguous [sw*255] float region ----
    const int nf4w = (sw * CH) >> 2;    // 4080 full tile, 1020 partial; both exact
    float* __restrict__ dst = out + (size_t)b * (size_t)(SP * CH) + (size_t)s0 * CH;
    for (int j = tid; j < nf4w; j += TPB) {
        f4 v = *(const f4*)(lds + j * 4);
        __builtin_nontemporal_store(v, (f4*)(dst + j * 4));
    }
}

extern "C" void kernel_launch(void* const* d_in, const int* in_sizes, int n_in,
                              void* d_out, int out_size, void* d_ws, size_t ws_size,
                              hipStream_t stream) {
    const float* pred    = (const float*)d_in[0];
    const float* anchors = (const float*)d_in[1];
    float* out = (float*)d_out;

    const int grid = BATCH * TILES_PER_B;   // 32 * 91 = 2912 blocks
    yolo_decode_kernel<<<grid, TPB, 0, stream>>>(pred, anchors, out);
}